// Round 13
// baseline (166.498 us; speedup 1.0000x reference)
//
#include <hip/hip_runtime.h>
#include <math.h>

typedef unsigned short ushort_t;
typedef __bf16 bf16x8 __attribute__((ext_vector_type(8)));
typedef float f32x4 __attribute__((ext_vector_type(4)));

// ---------------------------------------------------------------------------
// fp32 <-> bf16 helpers
// ---------------------------------------------------------------------------
__device__ __forceinline__ ushort_t f2b_rne(float f) {
    union { float f; unsigned int u; } c;
    c.f = f;
    unsigned int u = c.u;
    u += 0x7FFFu + ((u >> 16) & 1u);
    return (ushort_t)(u >> 16);
}
__device__ __forceinline__ float b2f(ushort_t v) {
    union { unsigned int u; float f; } c;
    c.u = ((unsigned int)v) << 16;
    return c.f;
}

// async global->LDS DMA, 16B per lane.
__device__ __forceinline__ void gl_lds16(const ushort_t* g, ushort_t* l) {
    __builtin_amdgcn_global_load_lds(
        (const __attribute__((address_space(1))) void*)g,
        (__attribute__((address_space(3))) void*)l, 16, 0, 0);
}

// ---------------------------------------------------------------------------
// prep: bf16 conversions + LN colsum zeroing. Vectorized 64x64 transposes
// (float4 loads + uint2 stores). R13: Wout now TRANSPOSED (for the out_gemm
// B^T convention) instead of flat-converted.
// Regions: converts | transposes[0,1200) (Wq 144 | Wk 144 | Wout 144 |
// Wv1 768) | colzero[1200,1208).
// ---------------------------------------------------------------------------
__global__ __launch_bounds__(256) void prep(
    const float* __restrict__ x, const float* __restrict__ context,
    const float* __restrict__ Wq, const float* __restrict__ Wk,
    const float* __restrict__ Wv1, const float* __restrict__ Wout,
    ushort_t* __restrict__ x_b, ushort_t* __restrict__ ctx_b,
    ushort_t* __restrict__ Wq_t, ushort_t* __restrict__ Wk_t,
    ushort_t* __restrict__ Wv1_t, ushort_t* __restrict__ Wout_t,
    float* __restrict__ colzero,   // colsum|colsumsq, 2*Mn floats
    int b, int n) {
    const int t = threadIdx.x;
    const int bid = blockIdx.x;
    const int nb_x = (b * 64 * 768 / 4) / 256;
    const int nb_c = (b * n * 768 / 4) / 256;

    if (bid < nb_x + nb_c) {  // flat converts (x, context)
        const float* in = (bid < nb_x) ? x : context;
        ushort_t* outp = (bid < nb_x) ? x_b : ctx_b;
        const int i = ((bid < nb_x) ? bid : (bid - nb_x)) * 256 + t;
        float4 v = ((const float4*)in)[i];
        ushort_t o[4] = {f2b_rne(v.x), f2b_rne(v.y), f2b_rne(v.z), f2b_rne(v.w)};
        *(uint2*)&outp[(size_t)i * 4] = *(uint2*)o;
        return;
    }

    int u = bid - nb_x - nb_c;
    if (u >= 1200) {  // zero colsum/colsumsq: 8 blocks x 256 x float4
        const int idx = (u - 1200) * 256 + t;
        ((float4*)colzero)[idx] = make_float4(0.f, 0.f, 0.f, 0.f);
        return;
    }

    // transposes, 64x64 tiles: Wq 144, Wk 144, Wout 144, Wv1 768
    const float* in;
    ushort_t* outp;
    int R = 768, C = 768;
    if (u < 144)        { in = Wq;   outp = Wq_t; }
    else if (u < 288)   { u -= 144;  in = Wk;   outp = Wk_t; }
    else if (u < 432)   { u -= 288;  in = Wout; outp = Wout_t; }
    else                { u -= 432;  in = Wv1;  outp = Wv1_t; C = 4096; }
    const int ct = C / 64;
    const int c0 = (u % ct) * 64, r0 = (u / ct) * 64;

    __shared__ float tt[64][65];
    const int lr = t >> 4;          // 0..15
    const int lc = (t & 15) * 4;    // 0,4,..,60
#pragma unroll
    for (int i = 0; i < 4; i++) {
        const float4 v =
            *(const float4*)&in[(size_t)(r0 + lr + 16 * i) * C + c0 + lc];
        tt[lr + 16 * i][lc + 0] = v.x;
        tt[lr + 16 * i][lc + 1] = v.y;
        tt[lr + 16 * i][lc + 2] = v.z;
        tt[lr + 16 * i][lc + 3] = v.w;
    }
    __syncthreads();
    const int rr = (t & 15) * 4;    // 0,4,..,60
    const int cc = t >> 4;          // 0..15
#pragma unroll
    for (int i = 0; i < 4; i++) {
        const int col = cc + 16 * i;
        ushort_t o[4] = {f2b_rne(tt[rr + 0][col]), f2b_rne(tt[rr + 1][col]),
                         f2b_rne(tt[rr + 2][col]), f2b_rne(tt[rr + 3][col])};
        *(uint2*)&outp[(size_t)(c0 + col) * R + r0 + rr] = *(uint2*)o;
    }
}

// ---------------------------------------------------------------------------
// gemm big tile (256x256): R2-verified. ring-4 / depth-3 counted vmcnt, BK=32,
// 8 waves, wave tile 128x64, two 16-MFMA phases per K-step.
// ---------------------------------------------------------------------------
__device__ __forceinline__ void gemm_tile_big(
    const ushort_t* __restrict__ A, const ushort_t* __restrict__ Bt,
    ushort_t* __restrict__ C, int N, int row0, int col0, ushort_t* lds) {
    constexpr int K = 768;
    constexpr int NSTEP = 24;
    constexpr int SLOT = 512 * 32;            // (256+256)*32 ushorts per slot

    const int t = threadIdx.x;
    const int lane = t & 63, wave = t >> 6;
    const int quad = lane >> 4, l15 = lane & 15;
    const int wm = (wave >> 2) * 128;
    const int wn = (wave & 3) * 64;

    // stage source: lane l covers row (l>>2), phys slot (l&3); pre-swizzled
    const int srow = lane >> 2;
    const int sslot = (lane & 3) ^ ((lane >> 3) & 3);
    const ushort_t* gA = A + (size_t)(row0 + wave * 32 + srow) * K + sslot * 8;
    const ushort_t* gB = Bt + (size_t)(col0 + wave * 32 + srow) * K + sslot * 8;
    const int ldsA = wave * 1024;
    const int ldsB = 256 * 32 + wave * 1024;

    // read side: logical slot quad at row -> phys quad ^ ((row>>1)&3)
    const int rslot = (quad ^ ((l15 >> 1) & 3)) * 8;
    const int abase = (wm + l15) * 32 + rslot;
    const int bbase = 256 * 32 + (wn + l15) * 32 + rslot;

    f32x4 acc[8][4] = {};
    bf16x8 af[8], bfr[4];

    auto STAGE_A = [&](int s) {
        const int rg = (s & 3) * SLOT;
        const int ko = s * 32;
        gl_lds16(gA + ko, lds + rg + ldsA);
        gl_lds16(gA + 16 * K + ko, lds + rg + ldsA + 512);
    };
    auto STAGE_B = [&](int s) {
        const int rg = (s & 3) * SLOT;
        const int ko = s * 32;
        gl_lds16(gB + ko, lds + rg + ldsB);
        gl_lds16(gB + 16 * K + ko, lds + rg + ldsB + 512);
    };
    auto READ_B = [&](int s) {
        const ushort_t* p = lds + (s & 3) * SLOT + bbase;
#pragma unroll
        for (int j = 0; j < 4; ++j) bfr[j] = *(const bf16x8*)&p[j * 512];
    };
    auto READ_A_LO = [&](int s) {
        const ushort_t* p = lds + (s & 3) * SLOT + abase;
#pragma unroll
        for (int i = 0; i < 4; ++i) af[i] = *(const bf16x8*)&p[i * 512];
    };
    auto READ_A_HI = [&](int s) {
        const ushort_t* p = lds + (s & 3) * SLOT + abase;
#pragma unroll
        for (int i = 4; i < 8; ++i) af[i] = *(const bf16x8*)&p[i * 512];
    };
    auto MFMA_LO = [&]() {
        __builtin_amdgcn_s_setprio(1);
#pragma unroll
        for (int i = 0; i < 4; ++i)
#pragma unroll
            for (int j = 0; j < 4; ++j)
                acc[i][j] = __builtin_amdgcn_mfma_f32_16x16x32_bf16(
                    af[i], bfr[j], acc[i][j], 0, 0, 0);
        __builtin_amdgcn_s_setprio(0);
    };
    auto MFMA_HI = [&]() {
        __builtin_amdgcn_s_setprio(1);
#pragma unroll
        for (int i = 4; i < 8; ++i)
#pragma unroll
            for (int j = 0; j < 4; ++j)
                acc[i][j] = __builtin_amdgcn_mfma_f32_16x16x32_bf16(
                    af[i], bfr[j], acc[i][j], 0, 0, 0);
        __builtin_amdgcn_s_setprio(0);
    };

    // prologue: tiles 0,1,2 in flight (12 loads/wave); tile 0 landed.
    STAGE_A(0); STAGE_B(0);
    STAGE_A(1); STAGE_B(1);
    STAGE_A(2); STAGE_B(2);
    asm volatile("s_waitcnt vmcnt(8)" ::: "memory");
    __builtin_amdgcn_s_barrier();

    for (int s = 0; s < NSTEP - 3; ++s) {
        // ---- phase A: 8 ds_read + A-stage + 16 MFMA ----
        READ_B(s);
        READ_A_LO(s);
        STAGE_A(s + 3);
        __builtin_amdgcn_sched_barrier(0);
        __builtin_amdgcn_s_barrier();
        asm volatile("s_waitcnt lgkmcnt(0)" ::: "memory");
        __builtin_amdgcn_sched_barrier(0);
        MFMA_LO();
        __builtin_amdgcn_sched_barrier(0);
        __builtin_amdgcn_s_barrier();
        // ---- phase B: 4 ds_read + B-stage + counted vmcnt + 16 MFMA ----
        READ_A_HI(s);
        STAGE_B(s + 3);
        asm volatile("s_waitcnt vmcnt(8)" ::: "memory");  // tile s+1 landed
        __builtin_amdgcn_sched_barrier(0);
        __builtin_amdgcn_s_barrier();
        asm volatile("s_waitcnt lgkmcnt(0)" ::: "memory");
        __builtin_amdgcn_sched_barrier(0);
        MFMA_HI();
        __builtin_amdgcn_sched_barrier(0);
        __builtin_amdgcn_s_barrier();
    }

    // epilogue: all tiles staged; drain once, then barrier-free compute.
    asm volatile("s_waitcnt vmcnt(0)" ::: "memory");
    __builtin_amdgcn_s_barrier();
#pragma unroll
    for (int s = NSTEP - 3; s < NSTEP; ++s) {
        READ_B(s);
        READ_A_LO(s);
        READ_A_HI(s);
        asm volatile("s_waitcnt lgkmcnt(0)" ::: "memory");
        __builtin_amdgcn_sched_barrier(0);
        MFMA_LO();
        MFMA_HI();
    }

    // C/D layout: col = lane&15, row = quad*4 + reg   [m89/m91]
#pragma unroll
    for (int i = 0; i < 8; ++i)
#pragma unroll
        for (int j = 0; j < 4; ++j)
#pragma unroll
            for (int r = 0; r < 4; ++r) {
                const int row = row0 + wm + i * 16 + quad * 4 + r;
                const int col = col0 + wn + j * 16 + l15;
                C[(size_t)row * N + col] = f2b_rne(acc[i][j][r]);
            }
}

// ---------------------------------------------------------------------------
// gemm small tile (128x128): R2-verified ring-4 depth-3 structure.
// OUT_F32: store f32 (for the final out GEMM) instead of bf16.
// ---------------------------------------------------------------------------
template <bool OUT_F32>
__device__ __forceinline__ void gemm_tile_small(
    const ushort_t* __restrict__ A, const ushort_t* __restrict__ Bt,
    void* __restrict__ Cv, int N, int row0, int col0, ushort_t* lds) {
    constexpr int K = 768;
    constexpr int NSTEP = 24;
    constexpr int SLOT = 256 * 32;

    const int t = threadIdx.x;
    const int lane = t & 63, wave = t >> 6;
    const int quad = lane >> 4, l15 = lane & 15;
    const int wm = (wave >> 2) * 64;
    const int wn = (wave & 3) * 32;

    const int srow = lane >> 2;
    const int sslot = (lane & 3) ^ ((lane >> 3) & 3);
    const ushort_t* gA = A + (size_t)(row0 + wave * 16 + srow) * K + sslot * 8;
    const ushort_t* gB = Bt + (size_t)(col0 + wave * 16 + srow) * K + sslot * 8;
    const int ldsA = wave * 512;
    const int ldsB = 128 * 32 + wave * 512;

    const int rslot = (quad ^ ((l15 >> 1) & 3)) * 8;
    const int abase = (wm + l15) * 32 + rslot;
    const int bbase = 128 * 32 + (wn + l15) * 32 + rslot;

    f32x4 acc[4][2] = {};

    auto STAGE = [&](int s) {
        const int rg = (s & 3) * SLOT;
        const int ko = s * 32;
        gl_lds16(gA + ko, lds + rg + ldsA);
        gl_lds16(gB + ko, lds + rg + ldsB);
    };

    auto COMPUTE = [&](int s) {
        const int rg = (s & 3) * SLOT;
        const ushort_t* pA = lds + rg + abase;
        const ushort_t* pB = lds + rg + bbase;
        bf16x8 af[4], bfr[2];
#pragma unroll
        for (int i = 0; i < 4; ++i) af[i] = *(const bf16x8*)&pA[i * 512];
#pragma unroll
        for (int j = 0; j < 2; ++j) bfr[j] = *(const bf16x8*)&pB[j * 512];
        __builtin_amdgcn_s_setprio(1);
#pragma unroll
        for (int i = 0; i < 4; ++i)
#pragma unroll
            for (int j = 0; j < 2; ++j)
                acc[i][j] = __builtin_amdgcn_mfma_f32_16x16x32_bf16(
                    af[i], bfr[j], acc[i][j], 0, 0, 0);
        __builtin_amdgcn_s_setprio(0);
    };

    STAGE(0); STAGE(1); STAGE(2);

    for (int s = 0; s < NSTEP - 3; ++s) {
        __builtin_amdgcn_sched_barrier(0);
        __builtin_amdgcn_s_barrier();
        STAGE(s + 3);
        asm volatile("s_waitcnt vmcnt(6)" ::: "memory");
        __builtin_amdgcn_s_barrier();
        __builtin_amdgcn_sched_barrier(0);
        COMPUTE(s);
    }
    __builtin_amdgcn_sched_barrier(0);
    __builtin_amdgcn_s_barrier();
    asm volatile("s_waitcnt vmcnt(0)" ::: "memory");
    __builtin_amdgcn_s_barrier();
    __builtin_amdgcn_sched_barrier(0);
    COMPUTE(NSTEP - 3);
    COMPUTE(NSTEP - 2);
    COMPUTE(NSTEP - 1);

#pragma unroll
    for (int i = 0; i < 4; ++i)
#pragma unroll
        for (int j = 0; j < 2; ++j)
#pragma unroll
            for (int r = 0; r < 4; ++r) {
                const int row = row0 + wm + i * 16 + quad * 4 + r;
                const int col = col0 + wn + j * 16 + l15;
                if constexpr (OUT_F32)
                    ((float*)Cv)[(size_t)row * N + col] = acc[i][j][r];
                else
                    ((ushort_t*)Cv)[(size_t)row * N + col] =
                        f2b_rne(acc[i][j][r]);
            }
}

__global__ __launch_bounds__(512, 2) void gemm_ring(
    const ushort_t* __restrict__ x_b, const ushort_t* __restrict__ ctx_b,
    const ushort_t* __restrict__ Wq_t, const ushort_t* __restrict__ Wk_t,
    const ushort_t* __restrict__ Wv1_t,
    ushort_t* __restrict__ qb, ushort_t* __restrict__ kb,
    ushort_t* __restrict__ h1t, int b, int n) {
    extern __shared__ ushort_t lds[];
    const int Mn = b * n;
    const int M = b * 64;
    const int nbig = 16 * (Mn / 256);         // h1^T: rank dim 4096 = 16 tiles
    const int nk = (Mn / 128) * 6;
    int u = blockIdx.x;
    if (u < nbig) {
        gemm_tile_big(Wv1_t, ctx_b, h1t, Mn, (u & 15) * 256, (u >> 4) * 256,
                      lds);
    } else if ((u -= nbig) < nk) {
        const int rt = Mn / 128;
        gemm_tile_small<false>(ctx_b, Wk_t, kb, 768, (u % rt) * 128,
                               (u / rt) * 128, lds);
    } else {
        u -= nk;
        const int rt = M / 128;
        gemm_tile_small<false>(x_b, Wq_t, qb, 768, (u % rt) * 128,
                               (u / rt) * 128, lds);
    }
}

// ---------------------------------------------------------------------------
// out_gemm: out[256][768] = oA[256][768] @ Wout (via Wout_t), f32 store.
// 12 blocks of the verified small-tile structure -- Wout is read ~2x total
// instead of 256x (the per-block 1.18MB stream the attn matvec paid).
// ---------------------------------------------------------------------------
__global__ __launch_bounds__(512, 2) void out_gemm(
    const ushort_t* __restrict__ oA, const ushort_t* __restrict__ Wout_t,
    float* __restrict__ out, int M) {
    extern __shared__ ushort_t lds[];
    const int rt = M / 128;
    gemm_tile_small<true>(oA, Wout_t, out, 768, (blockIdx.x % rt) * 128,
                          (blockIdx.x / rt) * 128, lds);
}

// ---------------------------------------------------------------------------
// scores_stats: region 0 (b*8*(n/128)): S = QK^T/sqrt(96).
// region 1 (256 blocks): LN col sums of h1t, 256x256 panels, bf16x8 loads.
// ---------------------------------------------------------------------------
__global__ __launch_bounds__(256) void scores_stats(
    const ushort_t* __restrict__ qb, const ushort_t* __restrict__ kb,
    const ushort_t* __restrict__ h1t, float* __restrict__ S,
    float* __restrict__ colsum, float* __restrict__ colsumsq,
    int b, int n, int Mn) {
    __shared__ ushort_t sb[192 * 104];
    const int t = threadIdx.x;
    const int nsc = b * 8 * (n / 128);

    if (blockIdx.x >= nsc) {  // ---- LN column-sum panel ----
        const int u = blockIdx.x - nsc;
        const int rc = u >> 4;
        const int cc = u & 15;
        const int cg = t & 31;
        const int rg = t >> 5;
        const ushort_t* p =
            h1t + (size_t)(rc * 256 + rg * 32) * Mn + cc * 256 + cg * 8;
        float s[8] = {}, s2[8] = {};
#pragma unroll 4
        for (int r = 0; r < 32; r++) {
            const bf16x8 v = *(const bf16x8*)&p[(size_t)r * Mn];
#pragma unroll
            for (int j = 0; j < 8; j++) {
                const float f = (float)v[j];
                s[j] += f;
                s2[j] += f * f;
            }
        }
        float* red = (float*)sb;
#pragma unroll
        for (int j = 0; j < 8; j++) {
            red[rg * 256 + cg * 8 + j] = s[j];
            red[2048 + rg * 256 + cg * 8 + j] = s2[j];
        }
        __syncthreads();
        float ts = 0.f, ts2 = 0.f;
#pragma unroll
        for (int g = 0; g < 8; g++) {
            ts += red[g * 256 + t];
            ts2 += red[2048 + g * 256 + t];
        }
        atomicAdd(&colsum[cc * 256 + t], ts);
        atomicAdd(&colsumsq[cc * 256 + t], ts2);
        return;
    }

    // ---- scores tile ----
    const int nt = n / 128;
    const int n0 = (blockIdx.x % nt) * 128;
    const int bh = blockIdx.x / nt;
    const int bb = bh >> 3, h = bh & 7;
    const int lane = t & 63, wave = t >> 6;
    const int quad = lane >> 4, l15 = lane & 15;
    const int wm = (wave >> 1) * 32;
    const int wn = (wave & 1) * 64;

    ushort_t* Qs = sb;
    ushort_t* Ks = sb + 64 * 104;

    for (int g = t; g < 768; g += 256) {
        const int r = g / 12, s = g - r * 12;
        *(bf16x8*)&Qs[r * 104 + s * 8] =
            *(const bf16x8*)&qb[(size_t)(bb * 64 + r) * 768 + h * 96 + s * 8];
    }
    for (int g = t; g < 1536; g += 256) {
        const int r = g / 12, s = g - r * 12;
        *(bf16x8*)&Ks[r * 104 + s * 8] =
            *(const bf16x8*)&kb[(size_t)(bb * n + n0 + r) * 768 + h * 96 + s * 8];
    }
    __syncthreads();

    f32x4 acc[2][4] = {};
#pragma unroll
    for (int ks = 0; ks < 3; ks++) {
        bf16x8 af[2], bfr[4];
#pragma unroll
        for (int i = 0; i < 2; i++)
            af[i] = *(const bf16x8*)&Qs[(wm + i * 16 + l15) * 104 + ks * 32 + quad * 8];
#pragma unroll
        for (int j = 0; j < 4; j++)
            bfr[j] = *(const bf16x8*)&Ks[(wn + j * 16 + l15) * 104 + ks * 32 + quad * 8];
#pragma unroll
        for (int i = 0; i < 2; i++)
#pragma unroll
            for (int j = 0; j < 4; j++)
                acc[i][j] = __builtin_amdgcn_mfma_f32_16x16x32_bf16(
                    af[i], bfr[j], acc[i][j], 0, 0, 0);
    }

    const float sc = 0.10206207261596575f;  // 1/sqrt(96)
    float* Sp = S + (size_t)bh * 64 * n;
#pragma unroll
    for (int i = 0; i < 2; i++)
#pragma unroll
        for (int j = 0; j < 4; j++)
#pragma unroll
            for (int r = 0; r < 4; r++) {
                const int row = wm + i * 16 + quad * 4 + r;
                const int col = n0 + wn + j * 16 + l15;
                Sp[(size_t)row * n + col] = acc[i][j][r] * sc;
            }
}

// ---------------------------------------------------------------------------
// attn_fused (R12 structure, R13 tail): one block per (b,qi), 1024 thr.
// Single-pass reg-cached softmax; PV K-split with direct h1t reads; ends at
// the Wc phase by writing the bf16-rounded row to oA (the Wout projection
// moved to out_gemm -- removes the per-block 1.18MB Wout stream).
// ---------------------------------------------------------------------------
__global__ __launch_bounds__(1024) void attn_fused(
    const float* __restrict__ S, const float* __restrict__ colsum,
    const float* __restrict__ colsumsq, const ushort_t* __restrict__ h1t,
    const float* __restrict__ ln_g, const float* __restrict__ ln_b,
    const float* __restrict__ Wc, ushort_t* __restrict__ oA,
    int n, int Mn) {
    const int bq = blockIdx.x;
    const int bb = bq >> 6, qi = bq & 63;
    const int tid = threadIdx.x;
    const int lane = tid & 63, wv = tid >> 6;   // wv 0..15
    const int quad = lane >> 4, l15 = lane & 15;

    __shared__ ushort_t sW[9 * 1032];   // rows 0..7 = w[h], row 8 = zeros
    __shared__ ushort_t sH[64 * 264];   // overlays: mu/rstd | PV-reduce
    __shared__ float sl[8], swmu[8];
    __shared__ float pm[16], pl[16], pwm[16];
    __shared__ float sA[512];

    float* sMu = (float*)sH;            // [1024] (dead after exp pass)
    float* sRs = (float*)sH + 1024;     // [1024]

    // LN stats from column sums
    for (int i = tid; i < n; i += 1024) {
        const float cs = colsum[bb * n + i];
        const float cq = colsumsq[bb * n + i];
        const float m = cs * (1.0f / 4096.0f);
        sMu[i] = m;
        sRs[i] = rsqrtf(cq * (1.0f / 4096.0f) - m * m + 1e-5f);
    }
    // zero row 8 of sW
    for (int i = tid; i < 1032; i += 1024) sW[8 * 1032 + i] = 0;
    __syncthreads();

    // softmax: head h = wv>>1; each wave handles half of n.
    const int h = wv >> 1;
    const int half = wv & 1;
    const int nh = n >> 1;
    const int i0 = half * nh;
    const float* Sp = S + ((size_t)(bb * 8 + h) * 64 + qi) * n;
    float l = 0.f, wmacc = 0.f;
    if (nh == 512) {
        // fast path: 8 S values/lane cached in registers (single S sweep).
        float sv[8];
        {
            float m = -1e30f;
#pragma unroll
            for (int k = 0; k < 8; k++) {
                sv[k] = Sp[i0 + lane + k * 64];
                m = fmaxf(m, sv[k]);
            }
#pragma unroll
            for (int off = 32; off > 0; off >>= 1)
                m = fmaxf(m, __shfl_down(m, off));
            if (lane == 0) pm[wv] = m;
        }
        __syncthreads();
        const float mh = fmaxf(pm[2 * h], pm[2 * h + 1]);
#pragma unroll
        for (int k = 0; k < 8; k++) {
            const int i = i0 + lane + k * 64;
            const float e = expf(sv[k] - mh);
            const float w = e * sRs[i];
            const ushort_t wb = f2b_rne(w);
            sW[h * 1032 + i] = wb;
            l += e;
            wmacc += b2f(wb) * sMu[i];
        }
    } else {
        // generic two-pass fallback
        {
            float m = -1e30f;
            for (int i = i0 + lane; i < i0 + nh; i += 64) m = fmaxf(m, Sp[i]);
#pragma unroll
            for (int off = 32; off > 0; off >>= 1)
                m = fmaxf(m, __shfl_down(m, off));
            if (lane == 0) pm[wv] = m;
        }
        __syncthreads();
        const float mh = fmaxf(pm[2 * h], pm[2 * h + 1]);
        for (int i = i0 + lane; i < i0 + nh; i += 64) {
            const float e = expf(Sp[i] - mh);
            const float w = e * sRs[i];
            const ushort_t wb = f2b_rne(w);
            sW[h * 1032 + i] = wb;
            l += e;
            wmacc += b2f(wb) * sMu[i];
        }
    }
#pragma unroll
    for (int off = 32; off > 0; off >>= 1) {
        l += __shfl_down(l, off);
        wmacc += __shfl_down(wmacc, off);
    }
    if (lane == 0) { pl[wv] = l; pwm[wv] = wmacc; }
    __syncthreads();   // sW complete; sMu/sRs dead from here
    if (tid < 8) {
        sl[tid] = pl[2 * tid] + pl[2 * tid + 1];
        swmu[tid] = pwm[2 * tid] + pwm[2 * tid + 1];
    }

    // PV via MFMA, K-split: wave wv -> col block jb, K-chunk kg (256 wide).
    const int mrow = (l15 < 8 ? l15 : 8) * 1032;
    const int jb = wv & 3;
    const int kg = wv >> 2;
    f32x4 acc = {};
    {
        const ushort_t* hp =
            h1t + (size_t)(qi * 64 + jb * 16 + l15) * Mn + bb * n + kg * 256 +
            quad * 8;
        const ushort_t* wp = sW + mrow + kg * 256 + quad * 8;
#pragma unroll
        for (int ks = 0; ks < 8; ks++) {
            const bf16x8 af = *(const bf16x8*)&wp[ks * 32];
            const bf16x8 bf = *(const bf16x8*)&hp[ks * 32];
            acc = __builtin_amdgcn_mfma_f32_16x16x32_bf16(af, bf, acc, 0, 0, 0);
        }
    }
    __syncthreads();   // accs final in regs; sH free for reduce
    float* red = (float*)sH;   // [16 waves][64 lanes][4] = 16KB
    *(f32x4*)&red[(size_t)(wv * 64 + lane) * 4] = acc;
    __syncthreads();

    // epilogue: waves 0..3 (kg=0) reduce the 4 K-partials for their jb, then
    // LN affine. wave jb holds cols jb*16+l15, rows quad*4+r.
    if (wv < 4) {
        f32x4 a = *(const f32x4*)&red[(size_t)(wv * 64 + lane) * 4];
#pragma unroll
        for (int g = 1; g < 4; g++) {
            const f32x4 p = *(const f32x4*)&red[(size_t)((g * 4 + wv) * 64 + lane) * 4];
#pragma unroll
            for (int r = 0; r < 4; r++) a[r] += p[r];
        }
#pragma unroll
        for (int r = 0; r < 4; r++) {
            const int hh = quad * 4 + r;
            if (hh < 8) {
                const int rr = wv * 16 + l15;
                const int c = qi * 64 + rr;
                sA[hh * 64 + rr] =
                    ln_g[c] * ((a[r] - swmu[hh]) / sl[hh]) + ln_b[c];
            }
        }
    }
    __syncthreads();

    // Wc apply -> bf16-rounded row straight to oA (out_gemm input).
    if (tid < 768) {
        const int d = tid;
        const int hh = d / 96;
        const float* wp = Wc + (size_t)qi * 49152 + d;
        float a = 0.f;
#pragma unroll
        for (int r = 0; r < 64; r++) a += sA[hh * 64 + r] * wp[(size_t)r * 768];
        oA[(size_t)bq * 768 + d] = f2b_rne(a);
    }
}

// ---------------------------------------------------------------------------
extern "C" void kernel_launch(void* const* d_in, const int* in_sizes, int n_in,
                              void* d_out, int out_size, void* d_ws, size_t ws_size,
                              hipStream_t stream) {
    const float* x       = (const float*)d_in[0];
    const float* context = (const float*)d_in[1];
    const float* Wq      = (const float*)d_in[2];
    const float* Wk      = (const float*)d_in[3];
    const float* Wv1     = (const float*)d_in[4];
    const float* ln_g    = (const float*)d_in[5];
    const float* ln_b    = (const float*)d_in[6];
    const float* Wc      = (const float*)d_in[7];
    const float* Wout    = (const float*)d_in[8];
    float* out = (float*)d_out;

    const int b = in_sizes[0] / (64 * 768);
    const int n = in_sizes[1] / (b * 768);
    const int M  = b * 64;     // 256
    const int Mn = b * n;      // 4096

    float* ws = (float*)d_ws;
    size_t off = 0;
    float* S       = ws + off;  off += (size_t)b * 8 * 64 * n;
    float* colsum  = ws + off;  off += (size_t)Mn;
    float* colsumsq= ws + off;  off += (size_t)Mn;

    ushort_t* us = (ushort_t*)(ws + off);
    size_t uo = 0;
    ushort_t* x_b    = us + uo;  uo += (size_t)M * 768;
    ushort_t* ctx_b  = us + uo;  uo += (size_t)Mn * 768;
    ushort_t* qb     = us + uo;  uo += (size_t)M * 768;
    ushort_t* kb     = us + uo;  uo += (size_t)Mn * 768;
    ushort_t* h1t    = us + uo;  uo += (size_t)Mn * 4096;   // [c][n_glob]
    ushort_t* Wq_t   = us + uo;  uo += (size_t)768 * 768;
    ushort_t* Wk_t   = us + uo;  uo += (size_t)768 * 768;
    ushort_t* Wv1_t  = us + uo;  uo += (size_t)4096 * 768;
    ushort_t* Wout_t = us + uo;  uo += (size_t)768 * 768;
    ushort_t* oA     = us + uo;  uo += (size_t)M * 768;

    // 1. conversions + zero LN accumulators (Wout transposed for out_gemm)
    const int nb_x = (M * 768 / 4) / 256;
    const int nb_c = (Mn * 768 / 4) / 256;
    prep<<<nb_x + nb_c + 1208, 256, 0, stream>>>(
        x, context, Wq, Wk, Wv1, Wout, x_b, ctx_b, Wq_t, Wk_t, Wv1_t, Wout_t,
        colsum, b, n);

    // 2. q, k, h1^T GEMMs (R2-verified schedule)
    const int nbig = 16 * (Mn / 256);
    const int nk = (Mn / 128) * 6;
    const int nq = (M / 128) * 6;
    static bool attr_done = false;
    if (!attr_done) {
        (void)hipFuncSetAttribute(reinterpret_cast<const void*>(&gemm_ring),
                                  hipFuncAttributeMaxDynamicSharedMemorySize,
                                  131072);
        (void)hipFuncSetAttribute(reinterpret_cast<const void*>(&out_gemm),
                                  hipFuncAttributeMaxDynamicSharedMemorySize,
                                  65536);
        attr_done = true;
    }
    gemm_ring<<<nbig + nk + nq, 512, 131072, stream>>>(
        x_b, ctx_b, Wq_t, Wk_t, Wv1_t, qb, kb, h1t, b, n);

    // 3. scores + LN column sums
    scores_stats<<<b * 8 * (n / 128) + 256, 256, 0, stream>>>(
        qb, kb, h1t, S, colsum, colsumsq, b, n, Mn);

    // 4. fused softmax + PV + LN affine + Wc -> oA (bf16)
    attn_fused<<<M, 1024, 0, stream>>>(S, colsum, colsumsq, h1t, ln_g, ln_b,
                                       Wc, oA, n, Mn);

    // 5. out = oA @ Wout (tiled GEMM: Wout read ~2x total, not 256x)
    out_gemm<<<(M / 128) * 6, 512, 65536, stream>>>(oA, Wout_t, out, M);
}

// Round 14
// 165.590 us; speedup vs baseline: 1.0055x; 1.0055x over previous
//
#include <hip/hip_runtime.h>
#include <math.h>

typedef unsigned short ushort_t;
typedef __bf16 bf16x8 __attribute__((ext_vector_type(8)));
typedef float f32x4 __attribute__((ext_vector_type(4)));

// ---------------------------------------------------------------------------
// fp32 <-> bf16 helpers
// ---------------------------------------------------------------------------
__device__ __forceinline__ ushort_t f2b_rne(float f) {
    union { float f; unsigned int u; } c;
    c.f = f;
    unsigned int u = c.u;
    u += 0x7FFFu + ((u >> 16) & 1u);
    return (ushort_t)(u >> 16);
}
__device__ __forceinline__ float b2f(ushort_t v) {
    union { unsigned int u; float f; } c;
    c.u = ((unsigned int)v) << 16;
    return c.f;
}

// async global->LDS DMA, 16B per lane.
__device__ __forceinline__ void gl_lds16(const ushort_t* g, ushort_t* l) {
    __builtin_amdgcn_global_load_lds(
        (const __attribute__((address_space(1))) void*)g,
        (__attribute__((address_space(3))) void*)l, 16, 0, 0);
}

// ---------------------------------------------------------------------------
// prep: bf16 conversions + LN colsum zeroing (R9-verified, vectorized
// 64x64 transposes: float4 loads + uint2 stores).
// ---------------------------------------------------------------------------
__global__ __launch_bounds__(256) void prep(
    const float* __restrict__ x, const float* __restrict__ context,
    const float* __restrict__ Wq, const float* __restrict__ Wk,
    const float* __restrict__ Wv1, const float* __restrict__ Wout,
    ushort_t* __restrict__ x_b, ushort_t* __restrict__ ctx_b,
    ushort_t* __restrict__ Wq_t, ushort_t* __restrict__ Wk_t,
    ushort_t* __restrict__ Wv1_t, ushort_t* __restrict__ Wout_b,
    float* __restrict__ colzero,   // colsum|colsumsq, 2*Mn floats
    int b, int n) {
    const int t = threadIdx.x;
    const int bid = blockIdx.x;
    const int nb_x = (b * 64 * 768 / 4) / 256;
    const int nb_c = (b * n * 768 / 4) / 256;

    if (bid < nb_x + nb_c) {  // flat converts (x, context)
        const float* in = (bid < nb_x) ? x : context;
        ushort_t* outp = (bid < nb_x) ? x_b : ctx_b;
        const int i = ((bid < nb_x) ? bid : (bid - nb_x)) * 256 + t;
        float4 v = ((const float4*)in)[i];
        ushort_t o[4] = {f2b_rne(v.x), f2b_rne(v.y), f2b_rne(v.z), f2b_rne(v.w)};
        *(uint2*)&outp[(size_t)i * 4] = *(uint2*)o;
        return;
    }

    int u = bid - nb_x - nb_c;
    if (u >= 1632) {  // zero colsum/colsumsq: 8 blocks x 256 x float4
        const int idx = (u - 1632) * 256 + t;
        ((float4*)colzero)[idx] = make_float4(0.f, 0.f, 0.f, 0.f);
        return;
    }
    if (u >= 1056) {  // Wout flat convert: 576 blocks x 1024 floats
        const int i = (u - 1056) * 256 + t;
        float4 v = ((const float4*)Wout)[i];
        ushort_t o[4] = {f2b_rne(v.x), f2b_rne(v.y), f2b_rne(v.z), f2b_rne(v.w)};
        *(uint2*)&Wout_b[(size_t)i * 4] = *(uint2*)o;
        return;
    }

    // transposes, 64x64 tiles: Wq 144, Wk 144, Wv1 768
    const float* in;
    ushort_t* outp;
    int R = 768, C = 768;
    if (u < 144)        { in = Wq;  outp = Wq_t; }
    else if (u < 288)   { u -= 144; in = Wk;  outp = Wk_t; }
    else                { u -= 288; in = Wv1; outp = Wv1_t; C = 4096; }
    const int ct = C / 64;
    const int c0 = (u % ct) * 64, r0 = (u / ct) * 64;

    __shared__ float tt[64][65];
    const int lr = t >> 4;          // 0..15
    const int lc = (t & 15) * 4;    // 0,4,..,60
#pragma unroll
    for (int i = 0; i < 4; i++) {
        const float4 v =
            *(const float4*)&in[(size_t)(r0 + lr + 16 * i) * C + c0 + lc];
        tt[lr + 16 * i][lc + 0] = v.x;
        tt[lr + 16 * i][lc + 1] = v.y;
        tt[lr + 16 * i][lc + 2] = v.z;
        tt[lr + 16 * i][lc + 3] = v.w;
    }
    __syncthreads();
    const int rr = (t & 15) * 4;    // 0,4,..,60
    const int cc = t >> 4;          // 0..15
#pragma unroll
    for (int i = 0; i < 4; i++) {
        const int col = cc + 16 * i;
        ushort_t o[4] = {f2b_rne(tt[rr + 0][col]), f2b_rne(tt[rr + 1][col]),
                         f2b_rne(tt[rr + 2][col]), f2b_rne(tt[rr + 3][col])};
        *(uint2*)&outp[(size_t)(c0 + col) * R + r0 + rr] = *(uint2*)o;
    }
}

// ---------------------------------------------------------------------------
// gemm big tile (256x256): R2-verified. ring-4 / depth-3 counted vmcnt, BK=32,
// 8 waves, wave tile 128x64, two 16-MFMA phases per K-step.
// ---------------------------------------------------------------------------
__device__ __forceinline__ void gemm_tile_big(
    const ushort_t* __restrict__ A, const ushort_t* __restrict__ Bt,
    ushort_t* __restrict__ C, int N, int row0, int col0, ushort_t* lds) {
    constexpr int K = 768;
    constexpr int NSTEP = 24;
    constexpr int SLOT = 512 * 32;            // (256+256)*32 ushorts per slot

    const int t = threadIdx.x;
    const int lane = t & 63, wave = t >> 6;
    const int quad = lane >> 4, l15 = lane & 15;
    const int wm = (wave >> 2) * 128;
    const int wn = (wave & 3) * 64;

    // stage source: lane l covers row (l>>2), phys slot (l&3); pre-swizzled
    const int srow = lane >> 2;
    const int sslot = (lane & 3) ^ ((lane >> 3) & 3);
    const ushort_t* gA = A + (size_t)(row0 + wave * 32 + srow) * K + sslot * 8;
    const ushort_t* gB = Bt + (size_t)(col0 + wave * 32 + srow) * K + sslot * 8;
    const int ldsA = wave * 1024;
    const int ldsB = 256 * 32 + wave * 1024;

    // read side: logical slot quad at row -> phys quad ^ ((row>>1)&3)
    const int rslot = (quad ^ ((l15 >> 1) & 3)) * 8;
    const int abase = (wm + l15) * 32 + rslot;
    const int bbase = 256 * 32 + (wn + l15) * 32 + rslot;

    f32x4 acc[8][4] = {};
    bf16x8 af[8], bfr[4];

    auto STAGE_A = [&](int s) {
        const int rg = (s & 3) * SLOT;
        const int ko = s * 32;
        gl_lds16(gA + ko, lds + rg + ldsA);
        gl_lds16(gA + 16 * K + ko, lds + rg + ldsA + 512);
    };
    auto STAGE_B = [&](int s) {
        const int rg = (s & 3) * SLOT;
        const int ko = s * 32;
        gl_lds16(gB + ko, lds + rg + ldsB);
        gl_lds16(gB + 16 * K + ko, lds + rg + ldsB + 512);
    };
    auto READ_B = [&](int s) {
        const ushort_t* p = lds + (s & 3) * SLOT + bbase;
#pragma unroll
        for (int j = 0; j < 4; ++j) bfr[j] = *(const bf16x8*)&p[j * 512];
    };
    auto READ_A_LO = [&](int s) {
        const ushort_t* p = lds + (s & 3) * SLOT + abase;
#pragma unroll
        for (int i = 0; i < 4; ++i) af[i] = *(const bf16x8*)&p[i * 512];
    };
    auto READ_A_HI = [&](int s) {
        const ushort_t* p = lds + (s & 3) * SLOT + abase;
#pragma unroll
        for (int i = 4; i < 8; ++i) af[i] = *(const bf16x8*)&p[i * 512];
    };
    auto MFMA_LO = [&]() {
        __builtin_amdgcn_s_setprio(1);
#pragma unroll
        for (int i = 0; i < 4; ++i)
#pragma unroll
            for (int j = 0; j < 4; ++j)
                acc[i][j] = __builtin_amdgcn_mfma_f32_16x16x32_bf16(
                    af[i], bfr[j], acc[i][j], 0, 0, 0);
        __builtin_amdgcn_s_setprio(0);
    };
    auto MFMA_HI = [&]() {
        __builtin_amdgcn_s_setprio(1);
#pragma unroll
        for (int i = 4; i < 8; ++i)
#pragma unroll
            for (int j = 0; j < 4; ++j)
                acc[i][j] = __builtin_amdgcn_mfma_f32_16x16x32_bf16(
                    af[i], bfr[j], acc[i][j], 0, 0, 0);
        __builtin_amdgcn_s_setprio(0);
    };

    // prologue: tiles 0,1,2 in flight (12 loads/wave); tile 0 landed.
    STAGE_A(0); STAGE_B(0);
    STAGE_A(1); STAGE_B(1);
    STAGE_A(2); STAGE_B(2);
    asm volatile("s_waitcnt vmcnt(8)" ::: "memory");
    __builtin_amdgcn_s_barrier();

    for (int s = 0; s < NSTEP - 3; ++s) {
        // ---- phase A: 8 ds_read + A-stage + 16 MFMA ----
        READ_B(s);
        READ_A_LO(s);
        STAGE_A(s + 3);
        __builtin_amdgcn_sched_barrier(0);
        __builtin_amdgcn_s_barrier();
        asm volatile("s_waitcnt lgkmcnt(0)" ::: "memory");
        __builtin_amdgcn_sched_barrier(0);
        MFMA_LO();
        __builtin_amdgcn_sched_barrier(0);
        __builtin_amdgcn_s_barrier();
        // ---- phase B: 4 ds_read + B-stage + counted vmcnt + 16 MFMA ----
        READ_A_HI(s);
        STAGE_B(s + 3);
        asm volatile("s_waitcnt vmcnt(8)" ::: "memory");  // tile s+1 landed
        __builtin_amdgcn_sched_barrier(0);
        __builtin_amdgcn_s_barrier();
        asm volatile("s_waitcnt lgkmcnt(0)" ::: "memory");
        __builtin_amdgcn_sched_barrier(0);
        MFMA_HI();
        __builtin_amdgcn_sched_barrier(0);
        __builtin_amdgcn_s_barrier();
    }

    // epilogue: all tiles staged; drain once, then barrier-free compute.
    asm volatile("s_waitcnt vmcnt(0)" ::: "memory");
    __builtin_amdgcn_s_barrier();
#pragma unroll
    for (int s = NSTEP - 3; s < NSTEP; ++s) {
        READ_B(s);
        READ_A_LO(s);
        READ_A_HI(s);
        asm volatile("s_waitcnt lgkmcnt(0)" ::: "memory");
        __builtin_amdgcn_sched_barrier(0);
        MFMA_LO();
        MFMA_HI();
    }

    // C/D layout: col = lane&15, row = quad*4 + reg   [m89/m91]
#pragma unroll
    for (int i = 0; i < 8; ++i)
#pragma unroll
        for (int j = 0; j < 4; ++j)
#pragma unroll
            for (int r = 0; r < 4; ++r) {
                const int row = row0 + wm + i * 16 + quad * 4 + r;
                const int col = col0 + wn + j * 16 + l15;
                C[(size_t)row * N + col] = f2b_rne(acc[i][j][r]);
            }
}

// ---------------------------------------------------------------------------
// gemm small tile (128x128): R2-verified ring-4 depth-3 structure.
// ---------------------------------------------------------------------------
__device__ __forceinline__ void gemm_tile_small(
    const ushort_t* __restrict__ A, const ushort_t* __restrict__ Bt,
    ushort_t* __restrict__ C, int N, int row0, int col0, ushort_t* lds) {
    constexpr int K = 768;
    constexpr int NSTEP = 24;
    constexpr int SLOT = 256 * 32;

    const int t = threadIdx.x;
    const int lane = t & 63, wave = t >> 6;
    const int quad = lane >> 4, l15 = lane & 15;
    const int wm = (wave >> 2) * 64;
    const int wn = (wave & 3) * 32;

    const int srow = lane >> 2;
    const int sslot = (lane & 3) ^ ((lane >> 3) & 3);
    const ushort_t* gA = A + (size_t)(row0 + wave * 16 + srow) * K + sslot * 8;
    const ushort_t* gB = Bt + (size_t)(col0 + wave * 16 + srow) * K + sslot * 8;
    const int ldsA = wave * 512;
    const int ldsB = 128 * 32 + wave * 512;

    const int rslot = (quad ^ ((l15 >> 1) & 3)) * 8;
    const int abase = (wm + l15) * 32 + rslot;
    const int bbase = 128 * 32 + (wn + l15) * 32 + rslot;

    f32x4 acc[4][2] = {};

    auto STAGE = [&](int s) {
        const int rg = (s & 3) * SLOT;
        const int ko = s * 32;
        gl_lds16(gA + ko, lds + rg + ldsA);
        gl_lds16(gB + ko, lds + rg + ldsB);
    };

    auto COMPUTE = [&](int s) {
        const int rg = (s & 3) * SLOT;
        const ushort_t* pA = lds + rg + abase;
        const ushort_t* pB = lds + rg + bbase;
        bf16x8 af[4], bfr[2];
#pragma unroll
        for (int i = 0; i < 4; ++i) af[i] = *(const bf16x8*)&pA[i * 512];
#pragma unroll
        for (int j = 0; j < 2; ++j) bfr[j] = *(const bf16x8*)&pB[j * 512];
        __builtin_amdgcn_s_setprio(1);
#pragma unroll
        for (int i = 0; i < 4; ++i)
#pragma unroll
            for (int j = 0; j < 2; ++j)
                acc[i][j] = __builtin_amdgcn_mfma_f32_16x16x32_bf16(
                    af[i], bfr[j], acc[i][j], 0, 0, 0);
        __builtin_amdgcn_s_setprio(0);
    };

    STAGE(0); STAGE(1); STAGE(2);

    for (int s = 0; s < NSTEP - 3; ++s) {
        __builtin_amdgcn_sched_barrier(0);
        __builtin_amdgcn_s_barrier();
        STAGE(s + 3);
        asm volatile("s_waitcnt vmcnt(6)" ::: "memory");
        __builtin_amdgcn_s_barrier();
        __builtin_amdgcn_sched_barrier(0);
        COMPUTE(s);
    }
    __builtin_amdgcn_sched_barrier(0);
    __builtin_amdgcn_s_barrier();
    asm volatile("s_waitcnt vmcnt(0)" ::: "memory");
    __builtin_amdgcn_s_barrier();
    __builtin_amdgcn_sched_barrier(0);
    COMPUTE(NSTEP - 3);
    COMPUTE(NSTEP - 2);
    COMPUTE(NSTEP - 1);

#pragma unroll
    for (int i = 0; i < 4; ++i)
#pragma unroll
        for (int j = 0; j < 2; ++j)
#pragma unroll
            for (int r = 0; r < 4; ++r) {
                const int row = row0 + wm + i * 16 + quad * 4 + r;
                const int col = col0 + wn + j * 16 + l15;
                C[(size_t)row * N + col] = f2b_rne(acc[i][j][r]);
            }
}

__global__ __launch_bounds__(512, 2) void gemm_ring(
    const ushort_t* __restrict__ x_b, const ushort_t* __restrict__ ctx_b,
    const ushort_t* __restrict__ Wq_t, const ushort_t* __restrict__ Wk_t,
    const ushort_t* __restrict__ Wv1_t,
    ushort_t* __restrict__ qb, ushort_t* __restrict__ kb,
    ushort_t* __restrict__ h1t, int b, int n) {
    extern __shared__ ushort_t lds[];
    const int Mn = b * n;
    const int M = b * 64;
    const int nbig = 16 * (Mn / 256);         // h1^T: rank dim 4096 = 16 tiles
    const int nk = (Mn / 128) * 6;
    int u = blockIdx.x;
    if (u < nbig) {
        gemm_tile_big(Wv1_t, ctx_b, h1t, Mn, (u & 15) * 256, (u >> 4) * 256,
                      lds);
    } else if ((u -= nbig) < nk) {
        const int rt = Mn / 128;
        gemm_tile_small(ctx_b, Wk_t, kb, 768, (u % rt) * 128, (u / rt) * 128,
                        lds);
    } else {
        u -= nk;
        const int rt = M / 128;
        gemm_tile_small(x_b, Wq_t, qb, 768, (u % rt) * 128, (u / rt) * 128,
                        lds);
    }
}

// ---------------------------------------------------------------------------
// scores_stats: region 0 (b*8*(n/128)): S = QK^T/sqrt(96).
// region 1 (256 blocks): LN col sums of h1t, 256x256 panels, bf16x8 loads.
// ---------------------------------------------------------------------------
__global__ __launch_bounds__(256) void scores_stats(
    const ushort_t* __restrict__ qb, const ushort_t* __restrict__ kb,
    const ushort_t* __restrict__ h1t, float* __restrict__ S,
    float* __restrict__ colsum, float* __restrict__ colsumsq,
    int b, int n, int Mn) {
    __shared__ ushort_t sb[192 * 104];
    const int t = threadIdx.x;
    const int nsc = b * 8 * (n / 128);

    if (blockIdx.x >= nsc) {  // ---- LN column-sum panel ----
        const int u = blockIdx.x - nsc;
        const int rc = u >> 4;
        const int cc = u & 15;
        const int cg = t & 31;
        const int rg = t >> 5;
        const ushort_t* p =
            h1t + (size_t)(rc * 256 + rg * 32) * Mn + cc * 256 + cg * 8;
        float s[8] = {}, s2[8] = {};
#pragma unroll 4
        for (int r = 0; r < 32; r++) {
            const bf16x8 v = *(const bf16x8*)&p[(size_t)r * Mn];
#pragma unroll
            for (int j = 0; j < 8; j++) {
                const float f = (float)v[j];
                s[j] += f;
                s2[j] += f * f;
            }
        }
        float* red = (float*)sb;
#pragma unroll
        for (int j = 0; j < 8; j++) {
            red[rg * 256 + cg * 8 + j] = s[j];
            red[2048 + rg * 256 + cg * 8 + j] = s2[j];
        }
        __syncthreads();
        float ts = 0.f, ts2 = 0.f;
#pragma unroll
        for (int g = 0; g < 8; g++) {
            ts += red[g * 256 + t];
            ts2 += red[2048 + g * 256 + t];
        }
        atomicAdd(&colsum[cc * 256 + t], ts);
        atomicAdd(&colsumsq[cc * 256 + t], ts2);
        return;
    }

    // ---- scores tile ----
    const int nt = n / 128;
    const int n0 = (blockIdx.x % nt) * 128;
    const int bh = blockIdx.x / nt;
    const int bb = bh >> 3, h = bh & 7;
    const int lane = t & 63, wave = t >> 6;
    const int quad = lane >> 4, l15 = lane & 15;
    const int wm = (wave >> 1) * 32;
    const int wn = (wave & 1) * 64;

    ushort_t* Qs = sb;
    ushort_t* Ks = sb + 64 * 104;

    for (int g = t; g < 768; g += 256) {
        const int r = g / 12, s = g - r * 12;
        *(bf16x8*)&Qs[r * 104 + s * 8] =
            *(const bf16x8*)&qb[(size_t)(bb * 64 + r) * 768 + h * 96 + s * 8];
    }
    for (int g = t; g < 1536; g += 256) {
        const int r = g / 12, s = g - r * 12;
        *(bf16x8*)&Ks[r * 104 + s * 8] =
            *(const bf16x8*)&kb[(size_t)(bb * n + n0 + r) * 768 + h * 96 + s * 8];
    }
    __syncthreads();

    f32x4 acc[2][4] = {};
#pragma unroll
    for (int ks = 0; ks < 3; ks++) {
        bf16x8 af[2], bfr[4];
#pragma unroll
        for (int i = 0; i < 2; i++)
            af[i] = *(const bf16x8*)&Qs[(wm + i * 16 + l15) * 104 + ks * 32 + quad * 8];
#pragma unroll
        for (int j = 0; j < 4; j++)
            bfr[j] = *(const bf16x8*)&Ks[(wn + j * 16 + l15) * 104 + ks * 32 + quad * 8];
#pragma unroll
        for (int i = 0; i < 2; i++)
#pragma unroll
            for (int j = 0; j < 4; j++)
                acc[i][j] = __builtin_amdgcn_mfma_f32_16x16x32_bf16(
                    af[i], bfr[j], acc[i][j], 0, 0, 0);
    }

    const float sc = 0.10206207261596575f;  // 1/sqrt(96)
    float* Sp = S + (size_t)bh * 64 * n;
#pragma unroll
    for (int i = 0; i < 2; i++)
#pragma unroll
        for (int j = 0; j < 4; j++)
#pragma unroll
            for (int r = 0; r < 4; r++) {
                const int row = wm + i * 16 + quad * 4 + r;
                const int col = n0 + wn + j * 16 + l15;
                Sp[(size_t)row * n + col] = acc[i][j][r] * sc;
            }
}

// ---------------------------------------------------------------------------
// attn_fused (R12-verified): one block per (b,qi), 1024 thr / 16 waves.
// Single-pass reg-cached softmax (8 S vals/lane); PV K-split across all 16
// waves with direct h1t B-fragment reads; one LDS reduce; LN affine + Wc +
// row-grouped Wout matvec.
// ---------------------------------------------------------------------------
__global__ __launch_bounds__(1024) void attn_fused(
    const float* __restrict__ S, const float* __restrict__ colsum,
    const float* __restrict__ colsumsq, const ushort_t* __restrict__ h1t,
    const float* __restrict__ ln_g, const float* __restrict__ ln_b,
    const float* __restrict__ Wc, const ushort_t* __restrict__ Wout_b,
    float* __restrict__ out, int n, int Mn) {
    const int bq = blockIdx.x;
    const int bb = bq >> 6, qi = bq & 63;
    const int tid = threadIdx.x;
    const int lane = tid & 63, wv = tid >> 6;   // wv 0..15
    const int quad = lane >> 4, l15 = lane & 15;

    __shared__ ushort_t sW[9 * 1032];   // rows 0..7 = w[h], row 8 = zeros
    __shared__ ushort_t sH[64 * 264];   // overlays: mu/rstd | PV-reduce | rbuf
    __shared__ float sl[8], swmu[8];
    __shared__ float pm[16], pl[16], pwm[16];
    __shared__ float sA[512];
    __shared__ float sO[768];           // Wc-applied row (bf16-rounded)

    float* sMu = (float*)sH;            // [1024] (dead after exp pass)
    float* sRs = (float*)sH + 1024;     // [1024]

    // LN stats from column sums
    for (int i = tid; i < n; i += 1024) {
        const float cs = colsum[bb * n + i];
        const float cq = colsumsq[bb * n + i];
        const float m = cs * (1.0f / 4096.0f);
        sMu[i] = m;
        sRs[i] = rsqrtf(cq * (1.0f / 4096.0f) - m * m + 1e-5f);
    }
    // zero row 8 of sW
    for (int i = tid; i < 1032; i += 1024) sW[8 * 1032 + i] = 0;
    __syncthreads();

    // softmax: head h = wv>>1; each wave handles half of n.
    const int h = wv >> 1;
    const int half = wv & 1;
    const int nh = n >> 1;
    const int i0 = half * nh;
    const float* Sp = S + ((size_t)(bb * 8 + h) * 64 + qi) * n;
    float l = 0.f, wmacc = 0.f;
    if (nh == 512) {
        // fast path: 8 S values/lane cached in registers (single S sweep).
        float sv[8];
        {
            float m = -1e30f;
#pragma unroll
            for (int k = 0; k < 8; k++) {
                sv[k] = Sp[i0 + lane + k * 64];
                m = fmaxf(m, sv[k]);
            }
#pragma unroll
            for (int off = 32; off > 0; off >>= 1)
                m = fmaxf(m, __shfl_down(m, off));
            if (lane == 0) pm[wv] = m;
        }
        __syncthreads();
        const float mh = fmaxf(pm[2 * h], pm[2 * h + 1]);
#pragma unroll
        for (int k = 0; k < 8; k++) {
            const int i = i0 + lane + k * 64;
            const float e = expf(sv[k] - mh);
            const float w = e * sRs[i];
            const ushort_t wb = f2b_rne(w);
            sW[h * 1032 + i] = wb;
            l += e;
            wmacc += b2f(wb) * sMu[i];
        }
    } else {
        // generic two-pass fallback
        {
            float m = -1e30f;
            for (int i = i0 + lane; i < i0 + nh; i += 64) m = fmaxf(m, Sp[i]);
#pragma unroll
            for (int off = 32; off > 0; off >>= 1)
                m = fmaxf(m, __shfl_down(m, off));
            if (lane == 0) pm[wv] = m;
        }
        __syncthreads();
        const float mh = fmaxf(pm[2 * h], pm[2 * h + 1]);
        for (int i = i0 + lane; i < i0 + nh; i += 64) {
            const float e = expf(Sp[i] - mh);
            const float w = e * sRs[i];
            const ushort_t wb = f2b_rne(w);
            sW[h * 1032 + i] = wb;
            l += e;
            wmacc += b2f(wb) * sMu[i];
        }
    }
#pragma unroll
    for (int off = 32; off > 0; off >>= 1) {
        l += __shfl_down(l, off);
        wmacc += __shfl_down(wmacc, off);
    }
    if (lane == 0) { pl[wv] = l; pwm[wv] = wmacc; }
    __syncthreads();   // sW complete; sMu/sRs dead from here
    if (tid < 8) {
        sl[tid] = pl[2 * tid] + pl[2 * tid + 1];
        swmu[tid] = pwm[2 * tid] + pwm[2 * tid + 1];
    }

    // PV via MFMA, K-split: wave wv -> col block jb, K-chunk kg (256 wide).
    // C[h(16)][r(64)] = w @ H^T; B-fragments straight from h1t (16B/lane).
    const int mrow = (l15 < 8 ? l15 : 8) * 1032;
    const int jb = wv & 3;
    const int kg = wv >> 2;
    f32x4 acc = {};
    {
        const ushort_t* hp =
            h1t + (size_t)(qi * 64 + jb * 16 + l15) * Mn + bb * n + kg * 256 +
            quad * 8;
        const ushort_t* wp = sW + mrow + kg * 256 + quad * 8;
#pragma unroll
        for (int ks = 0; ks < 8; ks++) {
            const bf16x8 af = *(const bf16x8*)&wp[ks * 32];
            const bf16x8 bf = *(const bf16x8*)&hp[ks * 32];
            acc = __builtin_amdgcn_mfma_f32_16x16x32_bf16(af, bf, acc, 0, 0, 0);
        }
    }
    __syncthreads();   // accs final in regs; sH free for reduce
    float* red = (float*)sH;   // [16 waves][64 lanes][4] = 16KB
    *(f32x4*)&red[(size_t)(wv * 64 + lane) * 4] = acc;
    __syncthreads();

    // epilogue: waves 0..3 (kg=0) reduce the 4 K-partials for their jb, then
    // LN affine. wave jb holds cols jb*16+l15, rows quad*4+r.
    if (wv < 4) {
        f32x4 a = *(const f32x4*)&red[(size_t)(wv * 64 + lane) * 4];
#pragma unroll
        for (int g = 1; g < 4; g++) {
            const f32x4 p = *(const f32x4*)&red[(size_t)((g * 4 + wv) * 64 + lane) * 4];
#pragma unroll
            for (int r = 0; r < 4; r++) a[r] += p[r];
        }
#pragma unroll
        for (int r = 0; r < 4; r++) {
            const int hh = quad * 4 + r;
            if (hh < 8) {
                const int rr = wv * 16 + l15;
                const int c = qi * 64 + rr;
                sA[hh * 64 + rr] =
                    ln_g[c] * ((a[r] - swmu[hh]) / sl[hh]) + ln_b[c];
            }
        }
    }
    __syncthreads();

    // Wc apply -> sO (bf16-rounded, fp32 storage for broadcast reads)
    for (int d = tid; d < 768; d += 1024) {
        const int hh = d / 96;
        const float* wp = Wc + (size_t)qi * 49152 + d;
        float a = 0.f;
#pragma unroll
        for (int r = 0; r < 64; r++) a += sA[hh * 64 + r] * wp[(size_t)r * 768];
        sO[d] = b2f(f2b_rne(a));
    }
    __syncthreads();

    // Row-grouped Wout matvec.
    float* rbuf = (float*)sH;  // 8*768 floats (red dead after epilogue)
    if (tid < 768) {
        const int r0 = tid / 96;
        const int c0 = (tid % 96) * 8;
        const ushort_t* wp = Wout_b + (size_t)(r0 * 96) * 768 + c0;
        float acc8[8] = {};
#pragma unroll 4
        for (int s = 0; s < 96; s++) {
            const float sv = sO[r0 * 96 + s];
            const bf16x8 w8 = *(const bf16x8*)&wp[(size_t)s * 768];
#pragma unroll
            for (int j = 0; j < 8; j++) acc8[j] += sv * (float)w8[j];
        }
#pragma unroll
        for (int j = 0; j < 8; j++) rbuf[r0 * 768 + c0 + j] = acc8[j];
    }
    __syncthreads();
    if (tid < 768) {
        float s = 0.f;
#pragma unroll
        for (int g = 0; g < 8; g++) s += rbuf[g * 768 + tid];
        out[(size_t)bq * 768 + tid] = s;
    }
}

// ---------------------------------------------------------------------------
extern "C" void kernel_launch(void* const* d_in, const int* in_sizes, int n_in,
                              void* d_out, int out_size, void* d_ws, size_t ws_size,
                              hipStream_t stream) {
    const float* x       = (const float*)d_in[0];
    const float* context = (const float*)d_in[1];
    const float* Wq      = (const float*)d_in[2];
    const float* Wk      = (const float*)d_in[3];
    const float* Wv1     = (const float*)d_in[4];
    const float* ln_g    = (const float*)d_in[5];
    const float* ln_b    = (const float*)d_in[6];
    const float* Wc      = (const float*)d_in[7];
    const float* Wout    = (const float*)d_in[8];
    float* out = (float*)d_out;

    const int b = in_sizes[0] / (64 * 768);
    const int n = in_sizes[1] / (b * 768);
    const int M  = b * 64;     // 256
    const int Mn = b * n;      // 4096

    float* ws = (float*)d_ws;
    size_t off = 0;
    float* S       = ws + off;  off += (size_t)b * 8 * 64 * n;
    float* colsum  = ws + off;  off += (size_t)Mn;
    float* colsumsq= ws + off;  off += (size_t)Mn;

    ushort_t* us = (ushort_t*)(ws + off);
    size_t uo = 0;
    ushort_t* x_b    = us + uo;  uo += (size_t)M * 768;
    ushort_t* ctx_b  = us + uo;  uo += (size_t)Mn * 768;
    ushort_t* qb     = us + uo;  uo += (size_t)M * 768;
    ushort_t* kb     = us + uo;  uo += (size_t)Mn * 768;
    ushort_t* h1t    = us + uo;  uo += (size_t)Mn * 4096;   // [c][n_glob]
    ushort_t* Wq_t   = us + uo;  uo += (size_t)768 * 768;
    ushort_t* Wk_t   = us + uo;  uo += (size_t)768 * 768;
    ushort_t* Wv1_t  = us + uo;  uo += (size_t)4096 * 768;
    ushort_t* Wout_b = us + uo;  uo += (size_t)768 * 768;

    // 1. conversions + zero LN accumulators (vectorized 64x64 transposes)
    const int nb_x = (M * 768 / 4) / 256;
    const int nb_c = (Mn * 768 / 4) / 256;
    prep<<<nb_x + nb_c + 1640, 256, 0, stream>>>(
        x, context, Wq, Wk, Wv1, Wout, x_b, ctx_b, Wq_t, Wk_t, Wv1_t, Wout_b,
        colsum, b, n);

    // 2. q, k, h1^T GEMMs (R2-verified schedule)
    const int nbig = 16 * (Mn / 256);
    const int nk = (Mn / 128) * 6;
    const int nq = (M / 128) * 6;
    static bool attr_done = false;
    if (!attr_done) {
        (void)hipFuncSetAttribute(reinterpret_cast<const void*>(&gemm_ring),
                                  hipFuncAttributeMaxDynamicSharedMemorySize,
                                  131072);
        attr_done = true;
    }
    gemm_ring<<<nbig + nk + nq, 512, 131072, stream>>>(
        x_b, ctx_b, Wq_t, Wk_t, Wv1_t, qb, kb, h1t, b, n);

    // 3. scores + LN column sums
    scores_stats<<<b * 8 * (n / 128) + 256, 256, 0, stream>>>(
        qb, kb, h1t, S, colsum, colsumsq, b, n, Mn);

    // 4. fused softmax (single-pass, reg-cached S) + PV (K-split, direct
    //    h1t reads) + LN affine + Wc + row-grouped Wout matvec
    attn_fused<<<M, 1024, 0, stream>>>(S, colsum, colsumsq, h1t, ln_g, ln_b,
                                       Wc, Wout_b, out, n, Mn);
}